// Round 1
// baseline (625.929 us; speedup 1.0000x reference)
//
#include <hip/hip_runtime.h>
#include <cfloat>

// Problem constants (from reference): FACTOR=3, IPS=64, BP=5
//   CENTER=72, LO=57, HI=87, NEW_CENTER=57, ALIGNED_LEN=192, L=220
#define LCOLS        220
#define WIN_LO       57
#define WIN_HI       86     // inclusive
#define ALIGNED_LEN_ 192
#define MAX_START    28     // L - ALIGNED_LEN
#define IPS_         64
#define NEW_CENTER_  57

// One wave (64 lanes) per row. Row = 880 B = 55 float4s, 16B aligned.
__global__ __launch_bounds__(256, 4) void peak_align_kernel(
    const float* __restrict__ in,
    float* __restrict__ out_spikes,   // [K, 64]
    float* __restrict__ out_mask,     // [K]
    int K)
{
    const int lane            = threadIdx.x & 63;
    const int wave_in_block   = threadIdx.x >> 6;
    const int waves_per_block = blockDim.x >> 6;
    const long long wave_id   = (long long)blockIdx.x * waves_per_block + wave_in_block;
    const long long nwaves    = (long long)gridDim.x * waves_per_block;

    for (long long r = wave_id; r < K; r += nwaves) {
        const float* row = in + r * (long long)LCOLS;
        const int c0 = lane * 4;

        float4 v = make_float4(-FLT_MAX, -FLT_MAX, -FLT_MAX, -FLT_MAX);
        if (lane < 55) v = *(const float4*)(row + c0);
        float e[4] = {v.x, v.y, v.z, v.w};

        // ---- argmax over window cols [57, 86], first occurrence ----
        float bv = -FLT_MAX; int bi = 0x7fffffff;
        #pragma unroll
        for (int k = 0; k < 4; ++k) {
            int c = c0 + k;
            if (c >= WIN_LO && c <= WIN_HI && e[k] > bv) { bv = e[k]; bi = c; }
        }
        #pragma unroll
        for (int off = 32; off >= 1; off >>= 1) {
            float ov = __shfl_xor(bv, off);
            int   oi = __shfl_xor(bi, off);
            if (ov > bv || (ov == bv && oi < bi)) { bv = ov; bi = oi; }
        }
        const int  index_max = bi;                     // in [57, 86]
        const int  start     = index_max - WIN_LO;     // in [0, 29]
        const bool in_bounds = (start <= MAX_START);
        const int  s         = start > MAX_START ? MAX_START : start;

        // ---- argmax over aligned cols [s, s+192), first occurrence ----
        float av = -FLT_MAX; int ai = 0x7fffffff;
        #pragma unroll
        for (int k = 0; k < 4; ++k) {
            int c = c0 + k;
            if (c >= s && c < s + ALIGNED_LEN_ && e[k] > av) { av = e[k]; ai = c; }
        }
        #pragma unroll
        for (int off = 32; off >= 1; off >>= 1) {
            float ov = __shfl_xor(av, off);
            int   oi = __shfl_xor(ai, off);
            if (ov > av || (ov == av && oi < ai)) { av = ov; ai = oi; }
        }
        const bool at_center = (ai == s + NEW_CENTER_);
        const bool valid     = at_center && in_bounds;

        // ---- downsample: out[j] = row[s + 3*j], j = lane in [0,64) ----
        // col c lives at source lane c>>2, element c&3; 4 shuffles + select.
        int   c   = s + 3 * lane;          // max 28 + 189 = 217 <= 219
        int   src = c >> 2;                // <= 54, always a loaded lane
        int   sub = c & 3;
        float g0 = __shfl(e[0], src);
        float g1 = __shfl(e[1], src);
        float g2 = __shfl(e[2], src);
        float g3 = __shfl(e[3], src);
        float dv = (sub == 0) ? g0 : (sub == 1) ? g1 : (sub == 2) ? g2 : g3;

        out_spikes[r * IPS_ + lane] = valid ? dv : 0.0f;
        if (lane == 0) out_mask[r] = valid ? 0.0f : 1.0f;  // removed_mask = ~valid
    }
}

extern "C" void kernel_launch(void* const* d_in, const int* in_sizes, int n_in,
                              void* d_out, int out_size, void* d_ws, size_t ws_size,
                              hipStream_t stream) {
    const float* in = (const float*)d_in[0];
    const int K = in_sizes[0] / LCOLS;

    float* out_spikes = (float*)d_out;
    float* out_mask   = out_spikes + (long long)K * IPS_;

    const int block = 256;                 // 4 waves/block
    const int grid  = 4096;                // 16384 waves, grid-stride over rows

    hipLaunchKernelGGL(peak_align_kernel, dim3(grid), dim3(block), 0, stream,
                       in, out_spikes, out_mask, K);
}